// Round 2
// baseline (2923.269 us; speedup 1.0000x reference)
//
#include <hip/hip_runtime.h>

constexpr int Bb = 2, Cc = 64, Hh = 192, Ww = 192, Gg = 4, Cg = 16;
constexpr int HW = Hh * Ww;
constexpr int OFFC = 72;   // G * 2 * K
constexpr int MODC = 36;   // G * K

__device__ __forceinline__ float sigm(float x) { return 1.f / (1.f + __expf(-x)); }

// Grouped offset conv: per group g, in = [warp[g*16:(g+1)*16], src[g*16:(g+1)*16]] (32 ch),
// weights [18,32,3,3], bias[18]; out channel g*18+oc. Then 100*sigmoid - 50.
// Writes f32 directly into the offset_map region of d_out.
__global__ __launch_bounds__(256) void offset_conv_kernel(
    const float* __restrict__ warp, const float* __restrict__ srcp,
    const float* __restrict__ ow, const float* __restrict__ ob,
    float* __restrict__ off_out)
{
    int tid = blockIdx.x * 256 + threadIdx.x;
    if (tid >= Bb * OFFC * HW) return;
    int w = tid % Ww;
    int h = (tid / Ww) % Hh;
    int c = (tid / HW) % OFFC;
    int b = tid / (HW * OFFC);
    int g = c / 18, oc = c % 18;
    float sum = ob[oc];
    int h0 = h - 1, w0 = w - 1;
    for (int half = 0; half < 2; ++half) {
        const float* basep = (half == 0 ? warp : srcp) + (size_t)(b * Cc + g * Cg) * HW;
        for (int ic = 0; ic < Cg; ++ic) {
            const float* plane = basep + (size_t)ic * HW;
            const float* wb = ow + (size_t)(oc * 32 + half * Cg + ic) * 9;
            #pragma unroll
            for (int kh = 0; kh < 3; ++kh) {
                int ih = h0 + kh;
                if ((unsigned)ih >= (unsigned)Hh) continue;
                #pragma unroll
                for (int kw = 0; kw < 3; ++kw) {
                    int iw = w0 + kw;
                    if ((unsigned)iw >= (unsigned)Ww) continue;
                    sum += plane[ih * Ww + iw] * wb[kh * 3 + kw];
                }
            }
        }
    }
    off_out[tid] = 100.f * sigm(sum) - 50.f;
}

// Modulator conv: 64 -> 36 channels, 3x3, pad 1, then 2*sigmoid. f32 to ws.
__global__ __launch_bounds__(256) void mod_conv_kernel(
    const float* __restrict__ warp, const float* __restrict__ mw,
    const float* __restrict__ mb, float* __restrict__ modf)
{
    int tid = blockIdx.x * 256 + threadIdx.x;
    if (tid >= Bb * MODC * HW) return;
    int w = tid % Ww;
    int h = (tid / Ww) % Hh;
    int c = (tid / HW) % MODC;
    int b = tid / (HW * MODC);
    float sum = mb[c];
    int h0 = h - 1, w0 = w - 1;
    for (int ic = 0; ic < Cc; ++ic) {
        const float* plane = warp + (size_t)(b * Cc + ic) * HW;
        const float* wb = mw + (size_t)(c * Cc + ic) * 9;
        #pragma unroll
        for (int kh = 0; kh < 3; ++kh) {
            int ih = h0 + kh;
            if ((unsigned)ih >= (unsigned)Hh) continue;
            #pragma unroll
            for (int kw = 0; kw < 3; ++kw) {
                int iw = w0 + kw;
                if ((unsigned)iw >= (unsigned)Ww) continue;
                sum += plane[ih * Ww + iw] * wb[kh * 3 + kw];
            }
        }
    }
    modf[tid] = 2.f * sigm(sum);
}

// Deformable conv: 1 wave per output pixel, 4 waves/block.
// Phase 1: lane=(g,c) computes 9 bilinear samples * mask -> LDS vals[576].
// Phase 2: lane=output channel o, dot(vals, reg_w[o, :]).
__global__ __launch_bounds__(256) void deform_kernel(
    const float* __restrict__ xin,
    const float* __restrict__ offm,   // f32 offsets (offset_map region of d_out)
    const float* __restrict__ modf,
    const float* __restrict__ rw, float* __restrict__ out)
{
    __shared__ float vals[4][576];
    int wave = threadIdx.x >> 6;
    int lane = threadIdx.x & 63;
    int pid = blockIdx.x * 4 + wave;   // B*H*W = 73728, divisible by 4
    int wo = pid % Ww;
    int ho = (pid / Ww) % Hh;
    int b = pid / HW;
    int g = lane >> 4, cc = lane & 15;
    const float* plane = xin + (size_t)(b * Cc + g * Cg + cc) * HW;
    #pragma unroll
    for (int k = 0; k < 9; ++k) {
        int oyi = ((b * OFFC + g * 18 + 2 * k) * Hh + ho) * Ww + wo;
        int oxi = oyi + HW;   // next channel
        float oy = offm[oyi];
        float ox = offm[oxi];
        float m  = modf[((b * MODC + g * 9 + k) * Hh + ho) * Ww + wo];
        float y = oy + (float)(k / 3) + (float)(ho - 1);
        float x = ox + (float)(k % 3) + (float)(wo - 1);
        float fy = floorf(y), fx = floorf(x);
        float ly = y - fy, lx = x - fx;
        int y0 = (int)fy, x0 = (int)fx;
        bool y0v = (unsigned)y0 < (unsigned)Hh;
        bool y1v = (unsigned)(y0 + 1) < (unsigned)Hh;
        bool x0v = (unsigned)x0 < (unsigned)Ww;
        bool x1v = (unsigned)(x0 + 1) < (unsigned)Ww;
        float v00 = (y0v && x0v) ? plane[y0 * Ww + x0] : 0.f;
        float v01 = (y0v && x1v) ? plane[y0 * Ww + x0 + 1] : 0.f;
        float v10 = (y1v && x0v) ? plane[(y0 + 1) * Ww + x0] : 0.f;
        float v11 = (y1v && x1v) ? plane[(y0 + 1) * Ww + x0 + 1] : 0.f;
        float val = ((1.f - ly) * (1.f - lx) * v00 + (1.f - ly) * lx * v01 +
                     ly * (1.f - lx) * v10 + ly * lx * v11) * m;
        vals[wave][lane * 9 + k] = val;
    }
    __syncthreads();
    float acc = 0.f;
    const float* wrow = rw + (size_t)lane * 576;   // reg_w[o, gc, k] flat
    const float* vv = vals[wave];
    for (int j = 0; j < 576; ++j)
        acc += vv[j] * wrow[j];
    out[((b * Cc + lane) * Hh + ho) * Ww + wo] = acc;
}

extern "C" void kernel_launch(void* const* d_in, const int* in_sizes, int n_in,
                              void* d_out, int out_size, void* d_ws, size_t ws_size,
                              hipStream_t stream)
{
    const float* warp = (const float*)d_in[0];
    const float* srcp = (const float*)d_in[1];
    const float* ow   = (const float*)d_in[2];
    const float* ob   = (const float*)d_in[3];
    const float* mw   = (const float*)d_in[4];
    const float* mb   = (const float*)d_in[5];
    const float* rw   = (const float*)d_in[6];

    float* out_x   = (float*)d_out;
    float* out_off = out_x + (size_t)Bb * Cc * HW;   // offset_map region (output 1)

    const int nMod = Bb * MODC * HW;   // 2,654,208 floats -> 10.6 MB in ws
    const int nOff = Bb * OFFC * HW;   // 5,308,416

    float* modf = (float*)d_ws;

    offset_conv_kernel<<<(nOff + 255) / 256, 256, 0, stream>>>(
        warp, srcp, ow, ob, out_off);
    mod_conv_kernel<<<(nMod + 255) / 256, 256, 0, stream>>>(warp, mw, mb, modf);
    deform_kernel<<<(Bb * HW) / 4, 256, 0, stream>>>(
        warp, out_off, modf, rw, out_x);
}

// Round 3
// 1155.692 us; speedup vs baseline: 2.5295x; 2.5295x over previous
//
#include <hip/hip_runtime.h>

constexpr int Bb = 2, Cc = 64, Hh = 192, Ww = 192, Gg = 4, Cg = 16;
constexpr int HW = Hh * Ww;
constexpr int OFFC = 72;   // G * 2 * K
constexpr int MODC = 36;   // G * K

__device__ __forceinline__ float sigm(float x) { return 1.f / (1.f + __expf(-x)); }

// Offset conv (grouped): thread = pixel, acc[18] output channels in regs,
// weights transposed into LDS, read as wave-uniform broadcast.
__global__ __launch_bounds__(256) void offset_conv2(
    const float* __restrict__ warp, const float* __restrict__ srcp,
    const float* __restrict__ ow, const float* __restrict__ ob,
    float* __restrict__ off_out)
{
    __shared__ float wT[144][20];   // rows padded to 20 for 16B alignment
    int g = blockIdx.y;
    int pg = blockIdx.x * 256 + threadIdx.x;   // B*HW total, uniform b per block
    int b = pg / HW, pix = pg % HW;
    int ho = pix / Ww, wo = pix % Ww;

    int  tidx[9];
    bool tv[9];
    #pragma unroll
    for (int kh = 0; kh < 3; ++kh)
        #pragma unroll
        for (int kw = 0; kw < 3; ++kw) {
            int ih = ho - 1 + kh, iw = wo - 1 + kw;
            bool v = ((unsigned)ih < (unsigned)Hh) && ((unsigned)iw < (unsigned)Ww);
            tv[kh * 3 + kw] = v;
            tidx[kh * 3 + kw] = v ? ih * Ww + iw : 0;
        }

    float acc[18];
    #pragma unroll
    for (int i = 0; i < 18; ++i) acc[i] = 0.f;

    for (int half = 0; half < 2; ++half) {
        __syncthreads();
        for (int idx = threadIdx.x; idx < 144 * 18; idx += 256) {
            int r = idx / 18, oo = idx % 18;
            wT[r][oo] = ow[oo * 288 + half * 144 + r];   // ow[oc][ic32][3][3]
        }
        __syncthreads();
        const float* basep = (half ? srcp : warp) + (size_t)(b * Cc + g * Cg) * HW;
        for (int ic = 0; ic < 16; ++ic) {
            const float* plane = basep + (size_t)ic * HW;
            #pragma unroll
            for (int t = 0; t < 9; ++t) {
                float v = tv[t] ? plane[tidx[t]] : 0.f;
                const float* wr = wT[ic * 9 + t];
                #pragma unroll
                for (int oo = 0; oo < 18; ++oo) acc[oo] += v * wr[oo];
            }
        }
    }
    #pragma unroll
    for (int oo = 0; oo < 18; ++oo) {
        float s = acc[oo] + ob[oo];
        off_out[(size_t)(b * OFFC + g * 18 + oo) * HW + pix] = 100.f * sigm(s) - 50.f;
    }
}

// Modulator conv: thread = pixel, half of 36 channels per block (acc[18]).
__global__ __launch_bounds__(256) void mod_conv2(
    const float* __restrict__ warp, const float* __restrict__ mw,
    const float* __restrict__ mb, float* __restrict__ modf)
{
    __shared__ float wT[576][20];   // 46 KB
    int c0 = blockIdx.y * 18;
    int pg = blockIdx.x * 256 + threadIdx.x;
    int b = pg / HW, pix = pg % HW;
    int ho = pix / Ww, wo = pix % Ww;

    for (int idx = threadIdx.x; idx < 576 * 18; idx += 256) {
        int r = idx / 18, oo = idx % 18;
        wT[r][oo] = mw[(size_t)(c0 + oo) * 576 + r];   // mw[mc][ic64][3][3]
    }

    int  tidx[9];
    bool tv[9];
    #pragma unroll
    for (int kh = 0; kh < 3; ++kh)
        #pragma unroll
        for (int kw = 0; kw < 3; ++kw) {
            int ih = ho - 1 + kh, iw = wo - 1 + kw;
            bool v = ((unsigned)ih < (unsigned)Hh) && ((unsigned)iw < (unsigned)Ww);
            tv[kh * 3 + kw] = v;
            tidx[kh * 3 + kw] = v ? ih * Ww + iw : 0;
        }
    __syncthreads();

    float acc[18];
    #pragma unroll
    for (int i = 0; i < 18; ++i) acc[i] = 0.f;

    const float* bp = warp + (size_t)b * Cc * HW;
    for (int ic = 0; ic < 64; ++ic) {
        const float* plane = bp + (size_t)ic * HW;
        #pragma unroll
        for (int t = 0; t < 9; ++t) {
            float v = tv[t] ? plane[tidx[t]] : 0.f;
            const float* wr = wT[ic * 9 + t];
            #pragma unroll
            for (int oo = 0; oo < 18; ++oo) acc[oo] += v * wr[oo];
        }
    }
    #pragma unroll
    for (int oo = 0; oo < 18; ++oo)
        modf[(size_t)(b * MODC + c0 + oo) * HW + pix] = 2.f * sigm(acc[oo] + mb[c0 + oo]);
}

// Deformable conv: thread = pixel, acc[32] = half the output channels.
// Bilinear weights (incl. mask & validity) computed once per (g,k);
// reg_w slice transposed into LDS per g, read as broadcast.
__global__ __launch_bounds__(256) void deform2(
    const float* __restrict__ xin, const float* __restrict__ offm,
    const float* __restrict__ modf, const float* __restrict__ rw,
    float* __restrict__ out)
{
    __shared__ float wT[144][32];   // 18 KB, rows 128B-aligned
    int o0 = blockIdx.y * 32;
    int pg = blockIdx.x * 256 + threadIdx.x;
    int b = pg / HW, pix = pg % HW;
    int ho = pix / Ww, wo = pix % Ww;

    float acc[32];
    #pragma unroll
    for (int i = 0; i < 32; ++i) acc[i] = 0.f;

    const float* xb = xin + (size_t)b * Cc * HW;

    for (int g = 0; g < Gg; ++g) {
        __syncthreads();
        for (int idx = threadIdx.x; idx < 144 * 32; idx += 256) {
            int r = idx >> 5, oo = idx & 31;
            wT[r][oo] = rw[(size_t)(o0 + oo) * 576 + g * 144 + r];   // rw[o][g][c][k]
        }
        __syncthreads();

        for (int k = 0; k < 9; ++k) {
            int oyc = b * OFFC + g * 18 + 2 * k;
            float oy = offm[(size_t)oyc * HW + pix];
            float ox = offm[(size_t)(oyc + 1) * HW + pix];
            float m  = modf[(size_t)(b * MODC + g * 9 + k) * HW + pix];
            float y = oy + (float)(k / 3) + (float)(ho - 1);
            float x = ox + (float)(k % 3) + (float)(wo - 1);
            float fy = floorf(y), fx = floorf(x);
            float ly = y - fy, lx = x - fx;
            int y0 = (int)fy, x0 = (int)fx;
            bool y0v = (unsigned)y0 < (unsigned)Hh, y1v = (unsigned)(y0 + 1) < (unsigned)Hh;
            bool x0v = (unsigned)x0 < (unsigned)Ww, x1v = (unsigned)(x0 + 1) < (unsigned)Ww;
            float w00 = (y0v && x0v) ? (1.f - ly) * (1.f - lx) * m : 0.f;
            float w01 = (y0v && x1v) ? (1.f - ly) * lx * m : 0.f;
            float w10 = (y1v && x0v) ? ly * (1.f - lx) * m : 0.f;
            float w11 = (y1v && x1v) ? ly * lx * m : 0.f;
            int iy0 = min(max(y0, 0), Hh - 1), iy1 = min(max(y0 + 1, 0), Hh - 1);
            int ix0 = min(max(x0, 0), Ww - 1), ix1 = min(max(x0 + 1, 0), Ww - 1);
            int i00 = iy0 * Ww + ix0, i01 = iy0 * Ww + ix1;
            int i10 = iy1 * Ww + ix0, i11 = iy1 * Ww + ix1;

            const float* gp = xb + (size_t)(g * Cg) * HW;
            for (int c = 0; c < 16; ++c) {
                const float* plane = gp + (size_t)c * HW;
                float val = w00 * plane[i00] + w01 * plane[i01] +
                            w10 * plane[i10] + w11 * plane[i11];
                const float* wr = wT[c * 9 + k];
                #pragma unroll
                for (int oo = 0; oo < 32; ++oo) acc[oo] += val * wr[oo];
            }
        }
    }
    #pragma unroll
    for (int oo = 0; oo < 32; ++oo)
        out[(size_t)(b * Cc + o0 + oo) * HW + pix] = acc[oo];
}

extern "C" void kernel_launch(void* const* d_in, const int* in_sizes, int n_in,
                              void* d_out, int out_size, void* d_ws, size_t ws_size,
                              hipStream_t stream)
{
    const float* warp = (const float*)d_in[0];
    const float* srcp = (const float*)d_in[1];
    const float* ow   = (const float*)d_in[2];
    const float* ob   = (const float*)d_in[3];
    const float* mw   = (const float*)d_in[4];
    const float* mb   = (const float*)d_in[5];
    const float* rw   = (const float*)d_in[6];

    float* out_x   = (float*)d_out;
    float* out_off = out_x + (size_t)Bb * Cc * HW;   // offset_map region (output 1)
    float* modf    = (float*)d_ws;                   // 10.6 MB scratch

    const int ptiles = (Bb * HW) / 256;   // 576

    offset_conv2<<<dim3(ptiles, Gg), 256, 0, stream>>>(warp, srcp, ow, ob, out_off);
    mod_conv2  <<<dim3(ptiles, 2),  256, 0, stream>>>(warp, mw, mb, modf);
    deform2    <<<dim3(ptiles, 2),  256, 0, stream>>>(warp, out_off, modf, rw, out_x);
}

// Round 5
// 527.941 us; speedup vs baseline: 5.5371x; 2.1891x over previous
//
#include <hip/hip_runtime.h>

constexpr int Bb = 2, Cc = 64, Hh = 192, Ww = 192, Gg = 4, Cg = 16;
constexpr int HW = Hh * Ww;
constexpr int OFFC = 72;   // G * 2 * K
constexpr int MODC = 36;   // G * K

__device__ __forceinline__ float sigm(float x) { return 1.f / (1.f + __expf(-x)); }

// ---------------- offset conv (grouped) ----------------
__global__ __launch_bounds__(256) void offset_conv2(
    const float* __restrict__ warp, const float* __restrict__ srcp,
    const float* __restrict__ ow, const float* __restrict__ ob,
    float* __restrict__ off_out)
{
    __shared__ float wT[144][20];
    int g = blockIdx.y;
    int pg = blockIdx.x * 256 + threadIdx.x;
    int b = pg / HW, pix = pg % HW;
    int ho = pix / Ww, wo = pix % Ww;

    int  tidx[9];
    bool tv[9];
    #pragma unroll
    for (int kh = 0; kh < 3; ++kh)
        #pragma unroll
        for (int kw = 0; kw < 3; ++kw) {
            int ih = ho - 1 + kh, iw = wo - 1 + kw;
            bool v = ((unsigned)ih < (unsigned)Hh) && ((unsigned)iw < (unsigned)Ww);
            tv[kh * 3 + kw] = v;
            tidx[kh * 3 + kw] = v ? ih * Ww + iw : 0;
        }

    float acc[18];
    #pragma unroll
    for (int i = 0; i < 18; ++i) acc[i] = 0.f;

    for (int half = 0; half < 2; ++half) {
        __syncthreads();
        for (int idx = threadIdx.x; idx < 144 * 18; idx += 256) {
            int r = idx / 18, oo = idx % 18;
            wT[r][oo] = ow[oo * 288 + half * 144 + r];
        }
        __syncthreads();
        const float* basep = (half ? srcp : warp) + (size_t)(b * Cc + g * Cg) * HW;
        for (int ic = 0; ic < 16; ++ic) {
            const float* plane = basep + (size_t)ic * HW;
            #pragma unroll
            for (int t = 0; t < 9; ++t) {
                float v = tv[t] ? plane[tidx[t]] : 0.f;
                const float* wr = wT[ic * 9 + t];
                #pragma unroll
                for (int oo = 0; oo < 18; ++oo) acc[oo] += v * wr[oo];
            }
        }
    }
    #pragma unroll
    for (int oo = 0; oo < 18; ++oo) {
        float s = acc[oo] + ob[oo];
        off_out[(size_t)(b * OFFC + g * 18 + oo) * HW + pix] = 100.f * sigm(s) - 50.f;
    }
}

// ---------------- modulator conv ----------------
__global__ __launch_bounds__(256) void mod_conv2(
    const float* __restrict__ warp, const float* __restrict__ mw,
    const float* __restrict__ mb, float* __restrict__ modf)
{
    __shared__ float wT[576][20];
    int c0 = blockIdx.y * 18;
    int pg = blockIdx.x * 256 + threadIdx.x;
    int b = pg / HW, pix = pg % HW;
    int ho = pix / Ww, wo = pix % Ww;

    for (int idx = threadIdx.x; idx < 576 * 18; idx += 256) {
        int r = idx / 18, oo = idx % 18;
        wT[r][oo] = mw[(size_t)(c0 + oo) * 576 + r];
    }

    int  tidx[9];
    bool tv[9];
    #pragma unroll
    for (int kh = 0; kh < 3; ++kh)
        #pragma unroll
        for (int kw = 0; kw < 3; ++kw) {
            int ih = ho - 1 + kh, iw = wo - 1 + kw;
            bool v = ((unsigned)ih < (unsigned)Hh) && ((unsigned)iw < (unsigned)Ww);
            tv[kh * 3 + kw] = v;
            tidx[kh * 3 + kw] = v ? ih * Ww + iw : 0;
        }
    __syncthreads();

    float acc[18];
    #pragma unroll
    for (int i = 0; i < 18; ++i) acc[i] = 0.f;

    const float* bp = warp + (size_t)b * Cc * HW;
    for (int ic = 0; ic < 64; ++ic) {
        const float* plane = bp + (size_t)ic * HW;
        #pragma unroll
        for (int t = 0; t < 9; ++t) {
            float v = tv[t] ? plane[tidx[t]] : 0.f;
            const float* wr = wT[ic * 9 + t];
            #pragma unroll
            for (int oo = 0; oo < 18; ++oo) acc[oo] += v * wr[oo];
        }
    }
    #pragma unroll
    for (int oo = 0; oo < 18; ++oo)
        modf[(size_t)(b * MODC + c0 + oo) * HW + pix] = 2.f * sigm(acc[oo] + mb[c0 + oo]);
}

// ---------------- x transpose: [B,C,H,W] -> [B,G,HW,16] ----------------
__global__ __launch_bounds__(256) void transpose_x(
    const float* __restrict__ x, float* __restrict__ xT)
{
    int tid = blockIdx.x * 256 + threadIdx.x;   // over B*G*HW
    int pix = tid % HW;
    int bg = tid / HW;          // b*G+g
    int b = bg >> 2, g = bg & 3;
    const float* src = x + (size_t)(b * Cc + g * Cg) * HW + pix;
    float4* dst = (float4*)(xT + (size_t)tid * 16);
    #pragma unroll
    for (int c4 = 0; c4 < 4; ++c4) {
        float4 v;
        v.x = src[(size_t)(c4 * 4 + 0) * HW];
        v.y = src[(size_t)(c4 * 4 + 1) * HW];
        v.z = src[(size_t)(c4 * 4 + 2) * HW];
        v.w = src[(size_t)(c4 * 4 + 3) * HW];
        dst[c4] = v;
    }
}

// ---------------- deformable conv, HWC taps, acc[64] ----------------
__global__ __launch_bounds__(256) void deform3(
    const float* __restrict__ xT, const float* __restrict__ offm,
    const float* __restrict__ modf, const float* __restrict__ rw,
    float* __restrict__ out)
{
    __shared__ float wT[144][64];   // 36 KB, per-g slice of rw, transposed
    int pg = blockIdx.x * 256 + threadIdx.x;
    int b = pg / HW, pix = pg % HW;
    int ho = pix / Ww, wo = pix % Ww;

    float acc[64];
    #pragma unroll
    for (int i = 0; i < 64; ++i) acc[i] = 0.f;

    for (int g = 0; g < Gg; ++g) {
        __syncthreads();
        for (int idx = threadIdx.x; idx < 144 * 64; idx += 256) {
            int r = idx >> 6, oo = idx & 63;
            wT[r][oo] = rw[(size_t)oo * 576 + g * 144 + r];   // rw[o][g][c][k]
        }
        __syncthreads();

        const float* xg = xT + (size_t)((b << 2) + g) * HW * 16;

        for (int k = 0; k < 9; ++k) {
            int oyc = b * OFFC + g * 18 + 2 * k;
            float oy = offm[(size_t)oyc * HW + pix];
            float ox = offm[(size_t)(oyc + 1) * HW + pix];
            float m  = modf[(size_t)(b * MODC + g * 9 + k) * HW + pix];
            float y = oy + (float)(k / 3) + (float)(ho - 1);
            float x = ox + (float)(k % 3) + (float)(wo - 1);
            float fy = floorf(y), fx = floorf(x);
            float ly = y - fy, lx = x - fx;
            int y0 = (int)fy, x0 = (int)fx;
            bool y0v = (unsigned)y0 < (unsigned)Hh, y1v = (unsigned)(y0 + 1) < (unsigned)Hh;
            bool x0v = (unsigned)x0 < (unsigned)Ww, x1v = (unsigned)(x0 + 1) < (unsigned)Ww;
            float w00 = (y0v && x0v) ? (1.f - ly) * (1.f - lx) * m : 0.f;
            float w01 = (y0v && x1v) ? (1.f - ly) * lx * m : 0.f;
            float w10 = (y1v && x0v) ? ly * (1.f - lx) * m : 0.f;
            float w11 = (y1v && x1v) ? ly * lx * m : 0.f;
            int iy0 = min(max(y0, 0), Hh - 1), iy1 = min(max(y0 + 1, 0), Hh - 1);
            int ix0 = min(max(x0, 0), Ww - 1), ix1 = min(max(x0 + 1, 0), Ww - 1);

            const float4* t00 = (const float4*)(xg + (size_t)(iy0 * Ww + ix0) * 16);
            const float4* t01 = (const float4*)(xg + (size_t)(iy0 * Ww + ix1) * 16);
            const float4* t10 = (const float4*)(xg + (size_t)(iy1 * Ww + ix0) * 16);
            const float4* t11 = (const float4*)(xg + (size_t)(iy1 * Ww + ix1) * 16);

            float val[16];
            #pragma unroll
            for (int c4 = 0; c4 < 4; ++c4) {
                float4 a = t00[c4], bb2 = t01[c4], c2 = t10[c4], d2 = t11[c4];
                val[c4 * 4 + 0] = w00 * a.x + w01 * bb2.x + w10 * c2.x + w11 * d2.x;
                val[c4 * 4 + 1] = w00 * a.y + w01 * bb2.y + w10 * c2.y + w11 * d2.y;
                val[c4 * 4 + 2] = w00 * a.z + w01 * bb2.z + w10 * c2.z + w11 * d2.z;
                val[c4 * 4 + 3] = w00 * a.w + w01 * bb2.w + w10 * c2.w + w11 * d2.w;
            }

            #pragma unroll
            for (int c = 0; c < 16; ++c) {
                float vc = val[c];
                const float4* wr = (const float4*)wT[c * 9 + k];
                #pragma unroll
                for (int o4 = 0; o4 < 16; ++o4) {
                    float4 w4 = wr[o4];
                    acc[o4 * 4 + 0] += vc * w4.x;
                    acc[o4 * 4 + 1] += vc * w4.y;
                    acc[o4 * 4 + 2] += vc * w4.z;
                    acc[o4 * 4 + 3] += vc * w4.w;
                }
            }
        }
    }
    #pragma unroll
    for (int oo = 0; oo < 64; ++oo)
        out[(size_t)(b * Cc + oo) * HW + pix] = acc[oo];
}

// ---------------- fallback deform (round-3 version, CHW taps) ----------------
__global__ __launch_bounds__(256) void deform2(
    const float* __restrict__ xin, const float* __restrict__ offm,
    const float* __restrict__ modf, const float* __restrict__ rw,
    float* __restrict__ out)
{
    __shared__ float wT[144][32];
    int o0 = blockIdx.y * 32;
    int pg = blockIdx.x * 256 + threadIdx.x;
    int b = pg / HW, pix = pg % HW;
    int ho = pix / Ww, wo = pix % Ww;

    float acc[32];
    #pragma unroll
    for (int i = 0; i < 32; ++i) acc[i] = 0.f;

    const float* xb = xin + (size_t)b * Cc * HW;

    for (int g = 0; g < Gg; ++g) {
        __syncthreads();
        for (int idx = threadIdx.x; idx < 144 * 32; idx += 256) {
            int r = idx >> 5, oo = idx & 31;
            wT[r][oo] = rw[(size_t)(o0 + oo) * 576 + g * 144 + r];
        }
        __syncthreads();
        for (int k = 0; k < 9; ++k) {
            int oyc = b * OFFC + g * 18 + 2 * k;
            float oy = offm[(size_t)oyc * HW + pix];
            float ox = offm[(size_t)(oyc + 1) * HW + pix];
            float m  = modf[(size_t)(b * MODC + g * 9 + k) * HW + pix];
            float y = oy + (float)(k / 3) + (float)(ho - 1);
            float x = ox + (float)(k % 3) + (float)(wo - 1);
            float fy = floorf(y), fx = floorf(x);
            float ly = y - fy, lx = x - fx;
            int y0 = (int)fy, x0 = (int)fx;
            bool y0v = (unsigned)y0 < (unsigned)Hh, y1v = (unsigned)(y0 + 1) < (unsigned)Hh;
            bool x0v = (unsigned)x0 < (unsigned)Ww, x1v = (unsigned)(x0 + 1) < (unsigned)Ww;
            float w00 = (y0v && x0v) ? (1.f - ly) * (1.f - lx) * m : 0.f;
            float w01 = (y0v && x1v) ? (1.f - ly) * lx * m : 0.f;
            float w10 = (y1v && x0v) ? ly * (1.f - lx) * m : 0.f;
            float w11 = (y1v && x1v) ? ly * lx * m : 0.f;
            int iy0 = min(max(y0, 0), Hh - 1), iy1 = min(max(y0 + 1, 0), Hh - 1);
            int ix0 = min(max(x0, 0), Ww - 1), ix1 = min(max(x0 + 1, 0), Ww - 1);
            int i00 = iy0 * Ww + ix0, i01 = iy0 * Ww + ix1;
            int i10 = iy1 * Ww + ix0, i11 = iy1 * Ww + ix1;

            const float* gp = xb + (size_t)(g * Cg) * HW;
            for (int c = 0; c < 16; ++c) {
                const float* plane = gp + (size_t)c * HW;
                float val = w00 * plane[i00] + w01 * plane[i01] +
                            w10 * plane[i10] + w11 * plane[i11];
                const float* wr = wT[c * 9 + k];
                #pragma unroll
                for (int oo = 0; oo < 32; ++oo) acc[oo] += val * wr[oo];
            }
        }
    }
    #pragma unroll
    for (int oo = 0; oo < 32; ++oo)
        out[(size_t)(b * Cc + o0 + oo) * HW + pix] = acc[oo];
}

extern "C" void kernel_launch(void* const* d_in, const int* in_sizes, int n_in,
                              void* d_out, int out_size, void* d_ws, size_t ws_size,
                              hipStream_t stream)
{
    const float* warp = (const float*)d_in[0];
    const float* srcp = (const float*)d_in[1];
    const float* ow   = (const float*)d_in[2];
    const float* ob   = (const float*)d_in[3];
    const float* mw   = (const float*)d_in[4];
    const float* mb   = (const float*)d_in[5];
    const float* rw   = (const float*)d_in[6];

    float* out_x   = (float*)d_out;
    float* out_off = out_x + (size_t)Bb * Cc * HW;

    const int nMod = Bb * MODC * HW;               // 2,654,208 floats
    const size_t nXT = (size_t)Bb * Gg * HW * Cg;  // 4,718,592 floats

    float* modf = (float*)d_ws;
    float* xT   = modf + nMod;
    bool bigws = ws_size >= (nMod + nXT) * sizeof(float);

    const int ptiles = (Bb * HW) / 256;   // 576
    const int ttiles = (Bb * Gg * HW) / 256;

    offset_conv2<<<dim3(ptiles, Gg), 256, 0, stream>>>(warp, srcp, ow, ob, out_off);
    mod_conv2  <<<dim3(ptiles, 2),  256, 0, stream>>>(warp, mw, mb, modf);
    if (bigws) {
        transpose_x<<<ttiles, 256, 0, stream>>>(warp, xT);
        deform3<<<ptiles, 256, 0, stream>>>(xT, out_off, modf, rw, out_x);
    } else {
        deform2<<<dim3(ptiles, 2), 256, 0, stream>>>(warp, out_off, modf, rw, out_x);
    }
}

// Round 6
// 523.510 us; speedup vs baseline: 5.5840x; 1.0085x over previous
//
#include <hip/hip_runtime.h>

constexpr int Bb = 2, Cc = 64, Hh = 192, Ww = 192, Gg = 4, Cg = 16;
constexpr int HW = Hh * Ww;
constexpr int BHW = Bb * HW;       // 73728
constexpr int OFFC = 72;           // G * 2 * K
constexpr int MODC = 36;           // G * K
constexpr int PT = BHW / 256;      // 288 pixel tiles

constexpr int ROLE_A_END = PT * Gg;            // 1152 offset-conv vblocks
constexpr int ROLE_B_END = ROLE_A_END + PT * 2; // +576 mod-conv vblocks
constexpr int ROLE_C_END = ROLE_B_END + PT * Gg; // +1152 transpose vblocks

__device__ __forceinline__ float sigm(float x) { return 1.f / (1.f + __expf(-x)); }

// ---------------- fused prep: offset conv + mod conv + x transpose ----------------
__global__ __launch_bounds__(256) void prep_kernel(
    const float* __restrict__ warp, const float* __restrict__ srcp,
    const float* __restrict__ ow, const float* __restrict__ ob,
    const float* __restrict__ mw, const float* __restrict__ mb,
    float* __restrict__ off_out, float* __restrict__ modf,
    float* __restrict__ xT, int do_xT)
{
    __shared__ float smem[576 * 20];   // 46 KB union
    int vb = blockIdx.x;

    if (vb < ROLE_A_END) {
        // ---- offset conv (grouped), g = vb / PT ----
        float (*wT)[20] = (float(*)[20])smem;
        int g = vb / PT;
        int pg = (vb % PT) * 256 + threadIdx.x;
        int b = pg / HW, pix = pg % HW;
        int ho = pix / Ww, wo = pix % Ww;

        int  tidx[9];
        bool tv[9];
        #pragma unroll
        for (int kh = 0; kh < 3; ++kh)
            #pragma unroll
            for (int kw = 0; kw < 3; ++kw) {
                int ih = ho - 1 + kh, iw = wo - 1 + kw;
                bool v = ((unsigned)ih < (unsigned)Hh) && ((unsigned)iw < (unsigned)Ww);
                tv[kh * 3 + kw] = v;
                tidx[kh * 3 + kw] = v ? ih * Ww + iw : 0;
            }

        float acc[18];
        #pragma unroll
        for (int i = 0; i < 18; ++i) acc[i] = 0.f;

        for (int half = 0; half < 2; ++half) {
            __syncthreads();
            for (int idx = threadIdx.x; idx < 144 * 18; idx += 256) {
                int r = idx / 18, oo = idx % 18;
                wT[r][oo] = ow[oo * 288 + half * 144 + r];
            }
            __syncthreads();
            const float* basep = (half ? srcp : warp) + (size_t)(b * Cc + g * Cg) * HW;
            for (int ic = 0; ic < 16; ++ic) {
                const float* plane = basep + (size_t)ic * HW;
                #pragma unroll
                for (int t = 0; t < 9; ++t) {
                    float v = tv[t] ? plane[tidx[t]] : 0.f;
                    const float* wr = wT[ic * 9 + t];
                    #pragma unroll
                    for (int oo = 0; oo < 18; ++oo) acc[oo] += v * wr[oo];
                }
            }
        }
        #pragma unroll
        for (int oo = 0; oo < 18; ++oo) {
            float s = acc[oo] + ob[oo];
            off_out[(size_t)(b * OFFC + g * 18 + oo) * HW + pix] = 100.f * sigm(s) - 50.f;
        }
    } else if (vb < ROLE_B_END) {
        // ---- mod conv, c0 = chunk*18 ----
        float (*wT)[20] = (float(*)[20])smem;
        int vb2 = vb - ROLE_A_END;
        int c0 = (vb2 / PT) * 18;
        int pg = (vb2 % PT) * 256 + threadIdx.x;
        int b = pg / HW, pix = pg % HW;
        int ho = pix / Ww, wo = pix % Ww;

        for (int idx = threadIdx.x; idx < 576 * 18; idx += 256) {
            int r = idx / 18, oo = idx % 18;
            wT[r][oo] = mw[(size_t)(c0 + oo) * 576 + r];
        }

        int  tidx[9];
        bool tv[9];
        #pragma unroll
        for (int kh = 0; kh < 3; ++kh)
            #pragma unroll
            for (int kw = 0; kw < 3; ++kw) {
                int ih = ho - 1 + kh, iw = wo - 1 + kw;
                bool v = ((unsigned)ih < (unsigned)Hh) && ((unsigned)iw < (unsigned)Ww);
                tv[kh * 3 + kw] = v;
                tidx[kh * 3 + kw] = v ? ih * Ww + iw : 0;
            }
        __syncthreads();

        float acc[18];
        #pragma unroll
        for (int i = 0; i < 18; ++i) acc[i] = 0.f;

        const float* bp = warp + (size_t)b * Cc * HW;
        for (int ic = 0; ic < 64; ++ic) {
            const float* plane = bp + (size_t)ic * HW;
            #pragma unroll
            for (int t = 0; t < 9; ++t) {
                float v = tv[t] ? plane[tidx[t]] : 0.f;
                const float* wr = wT[ic * 9 + t];
                #pragma unroll
                for (int oo = 0; oo < 18; ++oo) acc[oo] += v * wr[oo];
            }
        }
        #pragma unroll
        for (int oo = 0; oo < 18; ++oo)
            modf[(size_t)(b * MODC + c0 + oo) * HW + pix] = 2.f * sigm(acc[oo] + mb[c0 + oo]);
    } else {
        // ---- x transpose [B,C,H,W] -> [B,G,HW,16] ----
        if (!do_xT) return;
        int tid = (vb - ROLE_B_END) * 256 + threadIdx.x;   // over B*G*HW
        int pix = tid % HW;
        int bg = tid / HW;
        int b = bg >> 2, g = bg & 3;
        const float* src = warp + (size_t)(b * Cc + g * Cg) * HW + pix;
        float4* dst = (float4*)(xT + (size_t)tid * 16);
        #pragma unroll
        for (int c4 = 0; c4 < 4; ++c4) {
            float4 v;
            v.x = src[(size_t)(c4 * 4 + 0) * HW];
            v.y = src[(size_t)(c4 * 4 + 1) * HW];
            v.z = src[(size_t)(c4 * 4 + 2) * HW];
            v.w = src[(size_t)(c4 * 4 + 3) * HW];
            dst[c4] = v;
        }
    }
}

// ---------------- deform, one group per block, partial accumulate ----------------
// part layout: [g][b][64][HW]  (so reduce is a pure strided sum)
__global__ __launch_bounds__(256) void deform_g(
    const float* __restrict__ xT, const float* __restrict__ offm,
    const float* __restrict__ modf, const float* __restrict__ rw,
    float* __restrict__ part)
{
    __shared__ float wT[144][64];   // 36 KB, per-g slice of rw
    int g = blockIdx.y;
    int pg = blockIdx.x * 256 + threadIdx.x;
    int b = pg / HW, pix = pg % HW;
    int ho = pix / Ww, wo = pix % Ww;

    for (int idx = threadIdx.x; idx < 144 * 64; idx += 256) {
        int r = idx >> 6, oo = idx & 63;
        wT[r][oo] = rw[(size_t)oo * 576 + g * 144 + r];   // rw[o][g][c][k]
    }
    __syncthreads();

    float acc[64];
    #pragma unroll
    for (int i = 0; i < 64; ++i) acc[i] = 0.f;

    const float* xg = xT + (size_t)((b << 2) + g) * HW * 16;

    for (int k = 0; k < 9; ++k) {
        int oyc = b * OFFC + g * 18 + 2 * k;
        float oy = offm[(size_t)oyc * HW + pix];
        float ox = offm[(size_t)(oyc + 1) * HW + pix];
        float m  = modf[(size_t)(b * MODC + g * 9 + k) * HW + pix];
        float y = oy + (float)(k / 3) + (float)(ho - 1);
        float x = ox + (float)(k % 3) + (float)(wo - 1);
        float fy = floorf(y), fx = floorf(x);
        float ly = y - fy, lx = x - fx;
        int y0 = (int)fy, x0 = (int)fx;
        bool y0v = (unsigned)y0 < (unsigned)Hh, y1v = (unsigned)(y0 + 1) < (unsigned)Hh;
        bool x0v = (unsigned)x0 < (unsigned)Ww, x1v = (unsigned)(x0 + 1) < (unsigned)Ww;
        float w00 = (y0v && x0v) ? (1.f - ly) * (1.f - lx) * m : 0.f;
        float w01 = (y0v && x1v) ? (1.f - ly) * lx * m : 0.f;
        float w10 = (y1v && x0v) ? ly * (1.f - lx) * m : 0.f;
        float w11 = (y1v && x1v) ? ly * lx * m : 0.f;
        int iy0 = min(max(y0, 0), Hh - 1), iy1 = min(max(y0 + 1, 0), Hh - 1);
        int ix0 = min(max(x0, 0), Ww - 1), ix1 = min(max(x0 + 1, 0), Ww - 1);

        const float4* t00 = (const float4*)(xg + (size_t)(iy0 * Ww + ix0) * 16);
        const float4* t01 = (const float4*)(xg + (size_t)(iy0 * Ww + ix1) * 16);
        const float4* t10 = (const float4*)(xg + (size_t)(iy1 * Ww + ix0) * 16);
        const float4* t11 = (const float4*)(xg + (size_t)(iy1 * Ww + ix1) * 16);

        float val[16];
        #pragma unroll
        for (int c4 = 0; c4 < 4; ++c4) {
            float4 a = t00[c4], bb2 = t01[c4], c2 = t10[c4], d2 = t11[c4];
            val[c4 * 4 + 0] = w00 * a.x + w01 * bb2.x + w10 * c2.x + w11 * d2.x;
            val[c4 * 4 + 1] = w00 * a.y + w01 * bb2.y + w10 * c2.y + w11 * d2.y;
            val[c4 * 4 + 2] = w00 * a.z + w01 * bb2.z + w10 * c2.z + w11 * d2.z;
            val[c4 * 4 + 3] = w00 * a.w + w01 * bb2.w + w10 * c2.w + w11 * d2.w;
        }

        #pragma unroll
        for (int c = 0; c < 16; ++c) {
            float vc = val[c];
            const float4* wr = (const float4*)wT[c * 9 + k];
            #pragma unroll
            for (int o4 = 0; o4 < 16; ++o4) {
                float4 w4 = wr[o4];
                acc[o4 * 4 + 0] += vc * w4.x;
                acc[o4 * 4 + 1] += vc * w4.y;
                acc[o4 * 4 + 2] += vc * w4.z;
                acc[o4 * 4 + 3] += vc * w4.w;
            }
        }
    }
    float* pg_out = part + ((size_t)(g * Bb + b) * 64) * HW + pix;
    #pragma unroll
    for (int oo = 0; oo < 64; ++oo)
        pg_out[(size_t)oo * HW] = acc[oo];
}

// ---------------- sum the 4 group partials -> out ----------------
__global__ __launch_bounds__(256) void reduce4(
    const float* __restrict__ part, float* __restrict__ out)
{
    const size_t S = (size_t)Bb * 64 * HW / 4;   // float4 stride per g
    size_t j = (size_t)blockIdx.x * 256 + threadIdx.x;   // over Bb*64*HW/4
    const float4* p = (const float4*)part;
    float4 a = p[j], b2 = p[j + S], c = p[j + 2 * S], d = p[j + 3 * S];
    float4 s;
    s.x = (a.x + b2.x) + (c.x + d.x);
    s.y = (a.y + b2.y) + (c.y + d.y);
    s.z = (a.z + b2.z) + (c.z + d.z);
    s.w = (a.w + b2.w) + (c.w + d.w);
    ((float4*)out)[j] = s;
}

// ---------------- fallback deform3 (round-5 version, single pass) ----------------
__global__ __launch_bounds__(256) void deform3(
    const float* __restrict__ xT, const float* __restrict__ offm,
    const float* __restrict__ modf, const float* __restrict__ rw,
    float* __restrict__ out)
{
    __shared__ float wT[144][64];
    int pg = blockIdx.x * 256 + threadIdx.x;
    int b = pg / HW, pix = pg % HW;
    int ho = pix / Ww, wo = pix % Ww;

    float acc[64];
    #pragma unroll
    for (int i = 0; i < 64; ++i) acc[i] = 0.f;

    for (int g = 0; g < Gg; ++g) {
        __syncthreads();
        for (int idx = threadIdx.x; idx < 144 * 64; idx += 256) {
            int r = idx >> 6, oo = idx & 63;
            wT[r][oo] = rw[(size_t)oo * 576 + g * 144 + r];
        }
        __syncthreads();

        const float* xg = xT + (size_t)((b << 2) + g) * HW * 16;

        for (int k = 0; k < 9; ++k) {
            int oyc = b * OFFC + g * 18 + 2 * k;
            float oy = offm[(size_t)oyc * HW + pix];
            float ox = offm[(size_t)(oyc + 1) * HW + pix];
            float m  = modf[(size_t)(b * MODC + g * 9 + k) * HW + pix];
            float y = oy + (float)(k / 3) + (float)(ho - 1);
            float x = ox + (float)(k % 3) + (float)(wo - 1);
            float fy = floorf(y), fx = floorf(x);
            float ly = y - fy, lx = x - fx;
            int y0 = (int)fy, x0 = (int)fx;
            bool y0v = (unsigned)y0 < (unsigned)Hh, y1v = (unsigned)(y0 + 1) < (unsigned)Hh;
            bool x0v = (unsigned)x0 < (unsigned)Ww, x1v = (unsigned)(x0 + 1) < (unsigned)Ww;
            float w00 = (y0v && x0v) ? (1.f - ly) * (1.f - lx) * m : 0.f;
            float w01 = (y0v && x1v) ? (1.f - ly) * lx * m : 0.f;
            float w10 = (y1v && x0v) ? ly * (1.f - lx) * m : 0.f;
            float w11 = (y1v && x1v) ? ly * lx * m : 0.f;
            int iy0 = min(max(y0, 0), Hh - 1), iy1 = min(max(y0 + 1, 0), Hh - 1);
            int ix0 = min(max(x0, 0), Ww - 1), ix1 = min(max(x0 + 1, 0), Ww - 1);

            const float4* t00 = (const float4*)(xg + (size_t)(iy0 * Ww + ix0) * 16);
            const float4* t01 = (const float4*)(xg + (size_t)(iy0 * Ww + ix1) * 16);
            const float4* t10 = (const float4*)(xg + (size_t)(iy1 * Ww + ix0) * 16);
            const float4* t11 = (const float4*)(xg + (size_t)(iy1 * Ww + ix1) * 16);

            float val[16];
            #pragma unroll
            for (int c4 = 0; c4 < 4; ++c4) {
                float4 a = t00[c4], bb2 = t01[c4], c2 = t10[c4], d2 = t11[c4];
                val[c4 * 4 + 0] = w00 * a.x + w01 * bb2.x + w10 * c2.x + w11 * d2.x;
                val[c4 * 4 + 1] = w00 * a.y + w01 * bb2.y + w10 * c2.y + w11 * d2.y;
                val[c4 * 4 + 2] = w00 * a.z + w01 * bb2.z + w10 * c2.z + w11 * d2.z;
                val[c4 * 4 + 3] = w00 * a.w + w01 * bb2.w + w10 * c2.w + w11 * d2.w;
            }

            #pragma unroll
            for (int c = 0; c < 16; ++c) {
                float vc = val[c];
                const float4* wr = (const float4*)wT[c * 9 + k];
                #pragma unroll
                for (int o4 = 0; o4 < 16; ++o4) {
                    float4 w4 = wr[o4];
                    acc[o4 * 4 + 0] += vc * w4.x;
                    acc[o4 * 4 + 1] += vc * w4.y;
                    acc[o4 * 4 + 2] += vc * w4.z;
                    acc[o4 * 4 + 3] += vc * w4.w;
                }
            }
        }
    }
    #pragma unroll
    for (int oo = 0; oo < 64; ++oo)
        out[(size_t)(b * Cc + oo) * HW + pix] = acc[oo];
}

// ---------------- fallback deform2 (CHW taps, no ws needed beyond modf) ----------------
__global__ __launch_bounds__(256) void deform2(
    const float* __restrict__ xin, const float* __restrict__ offm,
    const float* __restrict__ modf, const float* __restrict__ rw,
    float* __restrict__ out)
{
    __shared__ float wT[144][32];
    int o0 = blockIdx.y * 32;
    int pg = blockIdx.x * 256 + threadIdx.x;
    int b = pg / HW, pix = pg % HW;
    int ho = pix / Ww, wo = pix % Ww;

    float acc[32];
    #pragma unroll
    for (int i = 0; i < 32; ++i) acc[i] = 0.f;

    const float* xb = xin + (size_t)b * Cc * HW;

    for (int g = 0; g < Gg; ++g) {
        __syncthreads();
        for (int idx = threadIdx.x; idx < 144 * 32; idx += 256) {
            int r = idx >> 5, oo = idx & 31;
            wT[r][oo] = rw[(size_t)(o0 + oo) * 576 + g * 144 + r];
        }
        __syncthreads();
        for (int k = 0; k < 9; ++k) {
            int oyc = b * OFFC + g * 18 + 2 * k;
            float oy = offm[(size_t)oyc * HW + pix];
            float ox = offm[(size_t)(oyc + 1) * HW + pix];
            float m  = modf[(size_t)(b * MODC + g * 9 + k) * HW + pix];
            float y = oy + (float)(k / 3) + (float)(ho - 1);
            float x = ox + (float)(k % 3) + (float)(wo - 1);
            float fy = floorf(y), fx = floorf(x);
            float ly = y - fy, lx = x - fx;
            int y0 = (int)fy, x0 = (int)fx;
            bool y0v = (unsigned)y0 < (unsigned)Hh, y1v = (unsigned)(y0 + 1) < (unsigned)Hh;
            bool x0v = (unsigned)x0 < (unsigned)Ww, x1v = (unsigned)(x0 + 1) < (unsigned)Ww;
            float w00 = (y0v && x0v) ? (1.f - ly) * (1.f - lx) * m : 0.f;
            float w01 = (y0v && x1v) ? (1.f - ly) * lx * m : 0.f;
            float w10 = (y1v && x0v) ? ly * (1.f - lx) * m : 0.f;
            float w11 = (y1v && x1v) ? ly * lx * m : 0.f;
            int iy0 = min(max(y0, 0), Hh - 1), iy1 = min(max(y0 + 1, 0), Hh - 1);
            int ix0 = min(max(x0, 0), Ww - 1), ix1 = min(max(x0 + 1, 0), Ww - 1);
            int i00 = iy0 * Ww + ix0, i01 = iy0 * Ww + ix1;
            int i10 = iy1 * Ww + ix0, i11 = iy1 * Ww + ix1;

            const float* gp = xb + (size_t)(g * Cg) * HW;
            for (int c = 0; c < 16; ++c) {
                const float* plane = gp + (size_t)c * HW;
                float val = w00 * plane[i00] + w01 * plane[i01] +
                            w10 * plane[i10] + w11 * plane[i11];
                const float* wr = wT[c * 9 + k];
                #pragma unroll
                for (int oo = 0; oo < 32; ++oo) acc[oo] += val * wr[oo];
            }
        }
    }
    #pragma unroll
    for (int oo = 0; oo < 32; ++oo)
        out[(size_t)(b * Cc + o0 + oo) * HW + pix] = acc[oo];
}

extern "C" void kernel_launch(void* const* d_in, const int* in_sizes, int n_in,
                              void* d_out, int out_size, void* d_ws, size_t ws_size,
                              hipStream_t stream)
{
    const float* warp = (const float*)d_in[0];
    const float* srcp = (const float*)d_in[1];
    const float* ow   = (const float*)d_in[2];
    const float* ob   = (const float*)d_in[3];
    const float* mw   = (const float*)d_in[4];
    const float* mb   = (const float*)d_in[5];
    const float* rw   = (const float*)d_in[6];

    float* out_x   = (float*)d_out;
    float* out_off = out_x + (size_t)Bb * Cc * HW;

    const size_t nMod  = (size_t)Bb * MODC * HW;      //  2,654,208 floats
    const size_t nXT   = (size_t)Bb * Gg * HW * Cg;   //  4,718,592 floats
    const size_t nPart = (size_t)Gg * Bb * 64 * HW;   // 18,874,368 floats

    float* modf = (float*)d_ws;
    float* xT   = modf + nMod;
    float* part = xT + nXT;

    bool midws = ws_size >= (nMod + nXT) * sizeof(float);           // 29.5 MB
    bool bigws = ws_size >= (nMod + nXT + nPart) * sizeof(float);   // 105 MB

    int prep_grid = midws ? ROLE_C_END : ROLE_B_END;
    prep_kernel<<<prep_grid, 256, 0, stream>>>(
        warp, srcp, ow, ob, mw, mb, out_off, modf, xT, (int)midws);

    if (bigws) {
        deform_g<<<dim3(PT, Gg), 256, 0, stream>>>(xT, out_off, modf, rw, part);
        reduce4<<<(Bb * 64 * HW) / 4 / 256, 256, 0, stream>>>(part, out_x);
    } else if (midws) {
        deform3<<<PT, 256, 0, stream>>>(xT, out_off, modf, rw, out_x);
    } else {
        deform2<<<dim3(PT, 2), 256, 0, stream>>>(warp, out_off, modf, rw, out_x);
    }
}

// Round 7
// 365.708 us; speedup vs baseline: 7.9935x; 1.4315x over previous
//
#include <hip/hip_runtime.h>
#include <hip/hip_bf16.h>

constexpr int Bb = 2, Cc = 64, Hh = 192, Ww = 192, Gg = 4, Cg = 16;
constexpr int HW = Hh * Ww;
constexpr int BHW = Bb * HW;       // 73728
constexpr int OFFC = 72;           // G * 2 * K
constexpr int MODC = 36;           // G * K
constexpr int PT = BHW / 256;      // 288 pixel tiles (prep)

constexpr int ROLE_A_END = PT * Gg;              // 1152 offset-conv vblocks
constexpr int ROLE_B_END = ROLE_A_END + PT * 2;  // +576 mod-conv vblocks
constexpr int ROLE_C_END = ROLE_B_END + PT * Gg; // +1152 transpose vblocks

// MFMA deform geometry
constexpr int ROWB = 1168;         // LDS row pitch bytes per pixel (584 bf16; conflict-free b128)

typedef __attribute__((ext_vector_type(8))) short short8;   // 8 bf16 in 4 VGPRs
typedef __attribute__((ext_vector_type(4))) float f32x4;

__device__ __forceinline__ float sigm(float x) { return 1.f / (1.f + __expf(-x)); }
__device__ __forceinline__ ushort f2bf(float f) {
    __hip_bfloat16 h = __float2bfloat16(f);
    union { __hip_bfloat16 h; ushort u; } x; x.h = h; return x.u;
}

// ---------------- fused prep: offset conv + mod conv + x transpose ----------------
__global__ __launch_bounds__(256) void prep_kernel(
    const float* __restrict__ warp, const float* __restrict__ srcp,
    const float* __restrict__ ow, const float* __restrict__ ob,
    const float* __restrict__ mw, const float* __restrict__ mb,
    float* __restrict__ off_out, float* __restrict__ modf,
    float* __restrict__ xT, int do_xT)
{
    __shared__ float smem[576 * 20];   // 46 KB union
    int vb = blockIdx.x;

    if (vb < ROLE_A_END) {
        float (*wT)[20] = (float(*)[20])smem;
        int g = vb / PT;
        int pg = (vb % PT) * 256 + threadIdx.x;
        int b = pg / HW, pix = pg % HW;
        int ho = pix / Ww, wo = pix % Ww;

        int  tidx[9];
        bool tv[9];
        #pragma unroll
        for (int kh = 0; kh < 3; ++kh)
            #pragma unroll
            for (int kw = 0; kw < 3; ++kw) {
                int ih = ho - 1 + kh, iw = wo - 1 + kw;
                bool v = ((unsigned)ih < (unsigned)Hh) && ((unsigned)iw < (unsigned)Ww);
                tv[kh * 3 + kw] = v;
                tidx[kh * 3 + kw] = v ? ih * Ww + iw : 0;
            }

        float acc[18];
        #pragma unroll
        for (int i = 0; i < 18; ++i) acc[i] = 0.f;

        for (int half = 0; half < 2; ++half) {
            __syncthreads();
            for (int idx = threadIdx.x; idx < 144 * 18; idx += 256) {
                int r = idx / 18, oo = idx % 18;
                wT[r][oo] = ow[oo * 288 + half * 144 + r];
            }
            __syncthreads();
            const float* basep = (half ? srcp : warp) + (size_t)(b * Cc + g * Cg) * HW;
            for (int ic = 0; ic < 16; ++ic) {
                const float* plane = basep + (size_t)ic * HW;
                #pragma unroll
                for (int t = 0; t < 9; ++t) {
                    float v = tv[t] ? plane[tidx[t]] : 0.f;
                    const float* wr = wT[ic * 9 + t];
                    #pragma unroll
                    for (int oo = 0; oo < 18; ++oo) acc[oo] += v * wr[oo];
                }
            }
        }
        #pragma unroll
        for (int oo = 0; oo < 18; ++oo) {
            float s = acc[oo] + ob[oo];
            off_out[(size_t)(b * OFFC + g * 18 + oo) * HW + pix] = 100.f * sigm(s) - 50.f;
        }
    } else if (vb < ROLE_B_END) {
        float (*wT)[20] = (float(*)[20])smem;
        int vb2 = vb - ROLE_A_END;
        int c0 = (vb2 / PT) * 18;
        int pg = (vb2 % PT) * 256 + threadIdx.x;
        int b = pg / HW, pix = pg % HW;
        int ho = pix / Ww, wo = pix % Ww;

        for (int idx = threadIdx.x; idx < 576 * 18; idx += 256) {
            int r = idx / 18, oo = idx % 18;
            wT[r][oo] = mw[(size_t)(c0 + oo) * 576 + r];
        }

        int  tidx[9];
        bool tv[9];
        #pragma unroll
        for (int kh = 0; kh < 3; ++kh)
            #pragma unroll
            for (int kw = 0; kw < 3; ++kw) {
                int ih = ho - 1 + kh, iw = wo - 1 + kw;
                bool v = ((unsigned)ih < (unsigned)Hh) && ((unsigned)iw < (unsigned)Ww);
                tv[kh * 3 + kw] = v;
                tidx[kh * 3 + kw] = v ? ih * Ww + iw : 0;
            }
        __syncthreads();

        float acc[18];
        #pragma unroll
        for (int i = 0; i < 18; ++i) acc[i] = 0.f;

        const float* bp = warp + (size_t)b * Cc * HW;
        for (int ic = 0; ic < 64; ++ic) {
            const float* plane = bp + (size_t)ic * HW;
            #pragma unroll
            for (int t = 0; t < 9; ++t) {
                float v = tv[t] ? plane[tidx[t]] : 0.f;
                const float* wr = wT[ic * 9 + t];
                #pragma unroll
                for (int oo = 0; oo < 18; ++oo) acc[oo] += v * wr[oo];
            }
        }
        #pragma unroll
        for (int oo = 0; oo < 18; ++oo)
            modf[(size_t)(b * MODC + c0 + oo) * HW + pix] = 2.f * sigm(acc[oo] + mb[c0 + oo]);
    } else {
        if (!do_xT) return;
        int tid = (vb - ROLE_B_END) * 256 + threadIdx.x;   // over B*G*HW
        int pix = tid % HW;
        int bg = tid / HW;
        int b = bg >> 2, g = bg & 3;
        const float* src = warp + (size_t)(b * Cc + g * Cg) * HW + pix;
        float4* dst = (float4*)(xT + (size_t)tid * 16);
        #pragma unroll
        for (int c4 = 0; c4 < 4; ++c4) {
            float4 v;
            v.x = src[(size_t)(c4 * 4 + 0) * HW];
            v.y = src[(size_t)(c4 * 4 + 1) * HW];
            v.z = src[(size_t)(c4 * 4 + 2) * HW];
            v.w = src[(size_t)(c4 * 4 + 3) * HW];
            dst[c4] = v;
        }
    }
}

// ---------------- pack reg_w into fragment-linear bf16 ----------------
// j' = (g*9+k)*16 + c ; A-frag: lane l of wave w, kstep s holds
// W'[o = w*16 + (l&15)][j' = s*32 + (l>>4)*8 + e], e=0..7, stored contiguously.
__global__ __launch_bounds__(256) void pack_w(
    const float* __restrict__ rw, ushort* __restrict__ wpk)
{
    int t = blockIdx.x * 256 + threadIdx.x;   // 64*576 = 36864
    if (t >= 64 * 576) return;
    int o = t / 576, jp = t % 576;
    int gk = jp >> 4, c = jp & 15;
    int g = gk / 9, k = gk % 9;
    float f = rw[(size_t)o * 576 + g * 144 + c * 9 + k];
    int w = o >> 4;
    int l = (o & 15) + (((jp & 31) >> 3) << 4);
    int s = jp >> 5, e = jp & 7;
    wpk[(((size_t)(w * 18 + s)) * 64 + l) * 8 + e] = f2bf(f);
}

// ---------------- deformable conv: f32 sampling -> LDS bf16 -> MFMA GEMM ----------------
// Block = 64 pixels, 4 waves. Wave wv samples group g=wv (9 k's) for all 64 px,
// then computes output rows [16wv, 16wv+16) x 64 px with 72 MFMAs.
__global__ __launch_bounds__(256) void deform_mfma(
    const float* __restrict__ xT, const float* __restrict__ offm,
    const float* __restrict__ modf, const ushort* __restrict__ wpk,
    float* __restrict__ out)
{
    __shared__ char Vs[64 * ROWB];   // 74.75 KB
    int lane = threadIdx.x & 63;
    int wv = threadIdx.x >> 6;
    int px0 = blockIdx.x * 64;        // global pixel base (over BHW); 64 | HW
    int b = px0 / HW, pix0 = px0 % HW;

    // A-fragments: 18 k-steps, 16 B per lane, wave reads contiguous 1 KB
    short8 afrag[18];
    #pragma unroll
    for (int s = 0; s < 18; ++s)
        afrag[s] = *(const short8*)(wpk + (((size_t)(wv * 18 + s)) * 64 + lane) * 8);

    // ---- phase 1: sampling (g = wv, k = 0..8, px = lane) ----
    {
        int pix = pix0 + lane;
        int ho = pix / Ww, wo = pix % Ww;
        int g = wv;
        const float* xg = xT + (size_t)((b << 2) + g) * HW * 16;

        for (int k = 0; k < 9; ++k) {
            int oyc = b * OFFC + g * 18 + 2 * k;
            float oy = offm[(size_t)oyc * HW + pix];
            float ox = offm[(size_t)(oyc + 1) * HW + pix];
            float m  = modf[(size_t)(b * MODC + g * 9 + k) * HW + pix];
            float y = oy + (float)(k / 3) + (float)(ho - 1);
            float x = ox + (float)(k % 3) + (float)(wo - 1);
            float fy = floorf(y), fx = floorf(x);
            float ly = y - fy, lx = x - fx;
            int y0 = (int)fy, x0 = (int)fx;
            bool y0v = (unsigned)y0 < (unsigned)Hh, y1v = (unsigned)(y0 + 1) < (unsigned)Hh;
            bool x0v = (unsigned)x0 < (unsigned)Ww, x1v = (unsigned)(x0 + 1) < (unsigned)Ww;
            float w00 = (y0v && x0v) ? (1.f - ly) * (1.f - lx) * m : 0.f;
            float w01 = (y0v && x1v) ? (1.f - ly) * lx * m : 0.f;
            float w10 = (y1v && x0v) ? ly * (1.f - lx) * m : 0.f;
            float w11 = (y1v && x1v) ? ly * lx * m : 0.f;
            int iy0 = min(max(y0, 0), Hh - 1), iy1 = min(max(y0 + 1, 0), Hh - 1);
            int ix0 = min(max(x0, 0), Ww - 1), ix1 = min(max(x0 + 1, 0), Ww - 1);

            const float4* t00 = (const float4*)(xg + (size_t)(iy0 * Ww + ix0) * 16);
            const float4* t01 = (const float4*)(xg + (size_t)(iy0 * Ww + ix1) * 16);
            const float4* t10 = (const float4*)(xg + (size_t)(iy1 * Ww + ix0) * 16);
            const float4* t11 = (const float4*)(xg + (size_t)(iy1 * Ww + ix1) * 16);

            float val[16];
            #pragma unroll
            for (int c4 = 0; c4 < 4; ++c4) {
                float4 a = t00[c4], b2 = t01[c4], c2 = t10[c4], d2 = t11[c4];
                val[c4 * 4 + 0] = w00 * a.x + w01 * b2.x + w10 * c2.x + w11 * d2.x;
                val[c4 * 4 + 1] = w00 * a.y + w01 * b2.y + w10 * c2.y + w11 * d2.y;
                val[c4 * 4 + 2] = w00 * a.z + w01 * b2.z + w10 * c2.z + w11 * d2.z;
                val[c4 * 4 + 3] = w00 * a.w + w01 * b2.w + w10 * c2.w + w11 * d2.w;
            }

            short8 v0, v1;
            #pragma unroll
            for (int e = 0; e < 8; ++e) {
                v0[e] = (short)f2bf(val[e]);
                v1[e] = (short)f2bf(val[8 + e]);
            }
            int gk = g * 9 + k;
            char* dst = Vs + (size_t)lane * ROWB + gk * 32;
            *(short8*)(dst)      = v0;
            *(short8*)(dst + 16) = v1;
        }
    }
    __syncthreads();

    // ---- phase 2: GEMM, wave wv -> o rows [16wv, 16wv+16) ----
    int r = lane & 15, grp = lane >> 4;
    f32x4 acc0 = {0.f, 0.f, 0.f, 0.f}, acc1 = acc0, acc2 = acc0, acc3 = acc0;

    #pragma unroll
    for (int s = 0; s < 18; ++s) {
        const char* base = Vs + (size_t)r * ROWB + s * 64 + grp * 16;
        short8 b0 = *(const short8*)(base + 0 * 16 * ROWB);
        short8 b1 = *(const short8*)(base + 1 * 16 * ROWB);
        short8 b2 = *(const short8*)(base + 2 * 16 * ROWB);
        short8 b3 = *(const short8*)(base + 3 * 16 * ROWB);
        acc0 = __builtin_amdgcn_mfma_f32_16x16x32_bf16(afrag[s], b0, acc0, 0, 0, 0);
        acc1 = __builtin_amdgcn_mfma_f32_16x16x32_bf16(afrag[s], b1, acc1, 0, 0, 0);
        acc2 = __builtin_amdgcn_mfma_f32_16x16x32_bf16(afrag[s], b2, acc2, 0, 0, 0);
        acc3 = __builtin_amdgcn_mfma_f32_16x16x32_bf16(afrag[s], b3, acc3, 0, 0, 0);
    }

    // D[row][col]: col = lane&15 (pixel), row = (lane>>4)*4 + reg (o offset)
    #pragma unroll
    for (int reg = 0; reg < 4; ++reg) {
        int o = wv * 16 + grp * 4 + reg;
        size_t obase = (size_t)(b * Cc + o) * HW + pix0 + r;
        out[obase + 0 * 16] = acc0[reg];
        out[obase + 1 * 16] = acc1[reg];
        out[obase + 2 * 16] = acc2[reg];
        out[obase + 3 * 16] = acc3[reg];
    }
}

// ---------------- fallback deform (CHW taps, needs only modf in ws) ----------------
__global__ __launch_bounds__(256) void deform2(
    const float* __restrict__ xin, const float* __restrict__ offm,
    const float* __restrict__ modf, const float* __restrict__ rw,
    float* __restrict__ out)
{
    __shared__ float wT[144][32];
    int o0 = blockIdx.y * 32;
    int pg = blockIdx.x * 256 + threadIdx.x;
    int b = pg / HW, pix = pg % HW;
    int ho = pix / Ww, wo = pix % Ww;

    float acc[32];
    #pragma unroll
    for (int i = 0; i < 32; ++i) acc[i] = 0.f;

    const float* xb = xin + (size_t)b * Cc * HW;

    for (int g = 0; g < Gg; ++g) {
        __syncthreads();
        for (int idx = threadIdx.x; idx < 144 * 32; idx += 256) {
            int r = idx >> 5, oo = idx & 31;
            wT[r][oo] = rw[(size_t)(o0 + oo) * 576 + g * 144 + r];
        }
        __syncthreads();
        for (int k = 0; k < 9; ++k) {
            int oyc = b * OFFC + g * 18 + 2 * k;
            float oy = offm[(size_t)oyc * HW + pix];
            float ox = offm[(size_t)(oyc + 1) * HW + pix];
            float m  = modf[(size_t)(b * MODC + g * 9 + k) * HW + pix];
            float y = oy + (float)(k / 3) + (float)(ho - 1);
            float x = ox + (float)(k % 3) + (float)(wo - 1);
            float fy = floorf(y), fx = floorf(x);
            float ly = y - fy, lx = x - fx;
            int y0 = (int)fy, x0 = (int)fx;
            bool y0v = (unsigned)y0 < (unsigned)Hh, y1v = (unsigned)(y0 + 1) < (unsigned)Hh;
            bool x0v = (unsigned)x0 < (unsigned)Ww, x1v = (unsigned)(x0 + 1) < (unsigned)Ww;
            float w00 = (y0v && x0v) ? (1.f - ly) * (1.f - lx) * m : 0.f;
            float w01 = (y0v && x1v) ? (1.f - ly) * lx * m : 0.f;
            float w10 = (y1v && x0v) ? ly * (1.f - lx) * m : 0.f;
            float w11 = (y1v && x1v) ? ly * lx * m : 0.f;
            int iy0 = min(max(y0, 0), Hh - 1), iy1 = min(max(y0 + 1, 0), Hh - 1);
            int ix0 = min(max(x0, 0), Ww - 1), ix1 = min(max(x0 + 1, 0), Ww - 1);
            int i00 = iy0 * Ww + ix0, i01 = iy0 * Ww + ix1;
            int i10 = iy1 * Ww + ix0, i11 = iy1 * Ww + ix1;

            const float* gp = xb + (size_t)(g * Cg) * HW;
            for (int c = 0; c < 16; ++c) {
                const float* plane = gp + (size_t)c * HW;
                float val = w00 * plane[i00] + w01 * plane[i01] +
                            w10 * plane[i10] + w11 * plane[i11];
                const float* wr = wT[c * 9 + k];
                #pragma unroll
                for (int oo = 0; oo < 32; ++oo) acc[oo] += val * wr[oo];
            }
        }
    }
    #pragma unroll
    for (int oo = 0; oo < 32; ++oo)
        out[(size_t)(b * Cc + o0 + oo) * HW + pix] = acc[oo];
}

extern "C" void kernel_launch(void* const* d_in, const int* in_sizes, int n_in,
                              void* d_out, int out_size, void* d_ws, size_t ws_size,
                              hipStream_t stream)
{
    const float* warp = (const float*)d_in[0];
    const float* srcp = (const float*)d_in[1];
    const float* ow   = (const float*)d_in[2];
    const float* ob   = (const float*)d_in[3];
    const float* mw   = (const float*)d_in[4];
    const float* mb   = (const float*)d_in[5];
    const float* rw   = (const float*)d_in[6];

    float* out_x   = (float*)d_out;
    float* out_off = out_x + (size_t)Bb * Cc * HW;

    const size_t nMod = (size_t)Bb * MODC * HW;      //  2,654,208 floats
    const size_t nXT  = (size_t)Bb * Gg * HW * Cg;   //  4,718,592 floats
    const size_t nWpk = 64 * 576;                     // ushorts (72 KB)

    float*  modf = (float*)d_ws;
    float*  xT   = modf + nMod;
    ushort* wpk  = (ushort*)(xT + nXT);

    bool midws = ws_size >= (nMod + nXT) * sizeof(float) + nWpk * sizeof(ushort);

    int prep_grid = midws ? ROLE_C_END : ROLE_B_END;
    prep_kernel<<<prep_grid, 256, 0, stream>>>(
        warp, srcp, ow, ob, mw, mb, out_off, modf, xT, (int)midws);

    if (midws) {
        pack_w<<<(64 * 576 + 255) / 256, 256, 0, stream>>>(rw, wpk);
        deform_mfma<<<BHW / 64, 256, 0, stream>>>(xT, out_off, modf, wpk, out_x);
    } else {
        deform2<<<dim3(PT, 2), 256, 0, stream>>>(warp, out_off, modf, rw, out_x);
    }
}